// Round 2
// baseline (44.059 us; speedup 1.0000x reference)
//
#include <hip/hip_runtime.h>

// GLIF spiking recurrence, T=4, x:(16,2048,1024) f32, out = final spike map.
// The harness validates against a float32 numpy recomputation ("ref=np"),
// and the output is a hard threshold (0/1) -> we must replicate the f32
// arithmetic chain per-op: IEEE f32, numpy order, NO fma contraction,
// sigmoid = 1/(1+exp_f32(-p)) with correctly-rounded f32 exp (via f64 exp).

#define CH   2048
#define LROW 1024
#define TS   4

__global__ __launch_bounds__(256) void glif_f32_kernel(
    const float* __restrict__ x,
    const float* __restrict__ alpha,
    const float* __restrict__ beta,
    const float* __restrict__ gamma,
    const float* __restrict__ tau,
    const float* __restrict__ Vth,
    const float* __restrict__ leak,
    const float* __restrict__ reVth,
    const float* __restrict__ conduct,
    float* __restrict__ out)
{
#pragma clang fp contract(off)
    __shared__ float sh[11];               // f32 sigmoids of the 11 params
    const int bid = blockIdx.x;            // b*2048 + c
    const int c   = bid & (CH - 1);
    const int tid = threadIdx.x;

    if (tid < 11) {
        float p;
        if      (tid < 4)   p = conduct[tid * CH + c];  // cond rows t=0..3
        else if (tid == 4)  p = tau[c];
        else if (tid == 5)  p = leak[c];
        else if (tid == 6)  p = reVth[c];
        else if (tid == 7)  p = Vth[c];
        else if (tid == 8)  p = alpha[c];
        else if (tid == 9)  p = beta[c];
        else                p = gamma[c];
        // f32 sigmoid chain with correctly-rounded f32 exp:
        // e = round_f32(exp_f64(-p)) ~= CR expf(-p); then f32 add + f32 div.
        const float e = (float)exp(-(double)p);
        sh[tid] = 1.0f / (1.0f + e);
    }
    __syncthreads();

    // Hard gates exactly as the reference: sigmoid(p) > 0.5 (strict, f32).
    const float al = (sh[8]  > 0.5f) ? 1.0f : 0.0f;
    const float be = (sh[9]  > 0.5f) ? 1.0f : 0.0f;
    const float ga = (sh[10] > 0.5f) ? 1.0f : 0.0f;

    // Per-channel constants, f32 chain exactly as numpy broadcasts them.
    const float T1 = 1.0f - al * (1.0f - sh[4]);   // (1 - al*(1-tau_s))
    const float Lc = (1.0f - al) * sh[5];          // (1-al)*leak_s
    const float Rc = (1.0f - ga) * sh[6];          // (1-ga)*reVth_s
    const float Vs = sh[7];                        // Vth_s
    float ic[TS];
    #pragma unroll
    for (int t = 0; t < TS; ++t)
        ic[t] = 1.0f - be * (1.0f - sh[t]);        // I-scale per timestep

    const size_t rowbase = (size_t)bid * LROW + (size_t)tid * 4;
    const float4 xv = *reinterpret_cast<const float4*>(x + rowbase);
    const float xs[4] = { xv.x, xv.y, xv.z, xv.w };
    float ov[4];

    #pragma unroll
    for (int e = 0; e < 4; ++e) {
        float u = 0.0f, o = 0.0f;
        #pragma unroll
        for (int t = 0; t < TS; ++t) {
            // numpy order: ((((T1*u)*g) - Lc) + x*ic) - (Rc*o), g exact {0,1}
            const float g  = 1.0f - ga * o;
            const float un = (((T1 * u) * g - Lc) + xs[e] * ic[t]) - Rc * o;
            o = ((un - Vs) > 0.0f) ? 1.0f : 0.0f;
            u = un;
        }
        ov[e] = o;
    }

    *reinterpret_cast<float4*>(out + rowbase) =
        make_float4(ov[0], ov[1], ov[2], ov[3]);
}

extern "C" void kernel_launch(void* const* d_in, const int* in_sizes, int n_in,
                              void* d_out, int out_size, void* d_ws, size_t ws_size,
                              hipStream_t stream) {
    const float* x       = (const float*)d_in[0];
    const float* alpha   = (const float*)d_in[1];
    const float* beta    = (const float*)d_in[2];
    const float* gamma   = (const float*)d_in[3];
    const float* tau     = (const float*)d_in[4];
    const float* Vth     = (const float*)d_in[5];
    const float* leak    = (const float*)d_in[6];
    const float* reVth   = (const float*)d_in[7];
    const float* conduct = (const float*)d_in[8];
    float* out = (float*)d_out;

    const int grid = in_sizes[0] / LROW;   // one block per (b, c) row
    glif_f32_kernel<<<grid, 256, 0, stream>>>(x, alpha, beta, gamma, tau, Vth,
                                              leak, reVth, conduct, out);
}